// Round 1
// baseline (674.076 us; speedup 1.0000x reference)
//
#include <hip/hip_runtime.h>
#include <cstdint>
#include <cstddef>

constexpr int BLK = 256;

static inline size_t ws_align(size_t x) { return (x + 255) & ~size_t(255); }

// ---------------- edge layout detect & convert ----------------
// If the device buffer actually holds int64 indices (values < 50000 => high
// words all zero), odd int32 words of the first 32 edges are all zero.
__global__ void k_detect(const int* __restrict__ ei, int* __restrict__ flag) {
  int allz = 1;
  for (int i = 0; i < 32; ++i) allz &= (ei[2 * i + 1] == 0) ? 1 : 0;
  flag[0] = allz;
}

__global__ void k_convert(const int* __restrict__ ei, const int* __restrict__ flag,
                          int* __restrict__ row, int* __restrict__ col, int E) {
  int i = blockIdx.x * BLK + threadIdx.x;
  if (i >= E) return;
  if (flag[0]) { row[i] = ei[2 * i]; col[i] = ei[2 * (E + i)]; }
  else         { row[i] = ei[i];     col[i] = ei[E + i]; }
}

// ---------------- degree, dis, scan, scatter (CSR build) ----------------
__global__ void k_deg(const int* __restrict__ col, int* __restrict__ deg, int E) {
  int i = blockIdx.x * BLK + threadIdx.x;
  if (i < E) atomicAdd(&deg[col[i]], 1);
}

__global__ void k_dis(const int* __restrict__ deg, float* __restrict__ dis, int n) {
  int i = blockIdx.x * BLK + threadIdx.x;
  if (i < n) dis[i] = 1.0f / sqrtf((float)(deg[i] + 1));  // +1 self loop, always > 0
}

// hierarchical exclusive scan of deg -> offs (196 blocks of 256)
__global__ void k_scan1(const int* __restrict__ deg, int* __restrict__ offs,
                        int* __restrict__ bsum, int n) {
  __shared__ int wsums[5];
  int i = blockIdx.x * BLK + threadIdx.x;
  int v = (i < n) ? deg[i] : 0;
  int lane = threadIdx.x & 63, w = threadIdx.x >> 6;
  int x = v;
  #pragma unroll
  for (int s = 1; s < 64; s <<= 1) { int t = __shfl_up(x, s); if (lane >= s) x += t; }
  if (lane == 63) wsums[w] = x;
  __syncthreads();
  if (threadIdx.x == 0) {
    int a = 0;
    for (int k = 0; k < 4; ++k) { int t = wsums[k]; wsums[k] = a; a += t; }
    wsums[4] = a;
  }
  __syncthreads();
  int incl = x + wsums[w];
  if (i < n) offs[i] = incl - v;         // exclusive
  if (threadIdx.x == 0) bsum[blockIdx.x] = wsums[4];
}

__global__ void k_scan2(int* __restrict__ bsum, int nb) {  // nb <= 256
  __shared__ int wsums[5];
  int v = (threadIdx.x < nb) ? bsum[threadIdx.x] : 0;
  int lane = threadIdx.x & 63, w = threadIdx.x >> 6;
  int x = v;
  #pragma unroll
  for (int s = 1; s < 64; s <<= 1) { int t = __shfl_up(x, s); if (lane >= s) x += t; }
  if (lane == 63) wsums[w] = x;
  __syncthreads();
  if (threadIdx.x == 0) {
    int a = 0;
    for (int k = 0; k < 4; ++k) { int t = wsums[k]; wsums[k] = a; a += t; }
    wsums[4] = a;
  }
  __syncthreads();
  int incl = x + wsums[w];
  if (threadIdx.x < nb) bsum[threadIdx.x] = incl - v;
}

__global__ void k_scan3(int* __restrict__ offs, const int* __restrict__ bsum,
                        int n, int E) {
  int i = blockIdx.x * BLK + threadIdx.x;
  if (i < n) offs[i] += bsum[i >> 8];
  if (i == 0) offs[n] = E;
}

__global__ void k_scatter(const int* __restrict__ row, const int* __restrict__ col,
                          const int* __restrict__ offs, int* __restrict__ cursor,
                          int* __restrict__ csr, int E) {
  int i = blockIdx.x * BLK + threadIdx.x;
  if (i >= E) return;
  int v = col[i];
  int p = atomicAdd(&cursor[v], 1);
  csr[offs[v] + p] = row[i];
}

// ---------------- GEMM with fused dis-scale ----------------
// C[i][j] = (sum_k A[i][k]*W[k][j]) * (dis ? dis[i] : 1)
template<int K, int NOUT, int TM, int TN, int KC>
__launch_bounds__(BLK)
__global__ void k_gemm(const float* __restrict__ A, const float* __restrict__ W,
                       const float* __restrict__ dis, float* __restrict__ C,
                       int ldc, int N) {
  constexpr int BX = NOUT / TN;   // threads along cols
  constexpr int BY = BLK / BX;    // thread rows
  constexpr int BM = BY * TM;     // rows per block
  __shared__ float As[BM][KC + 1];
  __shared__ float Ws[KC * NOUT];
  const int tid = threadIdx.x;
  const int tx = tid % BX, ty = tid / BX;
  const int row0 = blockIdx.x * BM;
  float acc[TM][TN];
  #pragma unroll
  for (int m = 0; m < TM; ++m)
    #pragma unroll
    for (int n = 0; n < TN; ++n) acc[m][n] = 0.f;

  for (int kb = 0; kb < K; kb += KC) {
    constexpr int TPR = KC / 4;       // float4 loaders per row
    constexpr int RPP = BLK / TPR;    // rows per pass
    #pragma unroll
    for (int r0 = 0; r0 < BM; r0 += RPP) {
      int r = r0 + tid / TPR;
      int c = (tid % TPR) * 4;
      int gr = row0 + r;
      float4 v = make_float4(0.f, 0.f, 0.f, 0.f);
      if (gr < N) v = *(const float4*)&A[(size_t)gr * K + kb + c];
      As[r][c] = v.x; As[r][c + 1] = v.y; As[r][c + 2] = v.z; As[r][c + 3] = v.w;
    }
    const float4* Wsrc = (const float4*)(W + (size_t)kb * NOUT);
    constexpr int WTOT = KC * NOUT / 4;
    for (int t = tid; t < WTOT; t += BLK) ((float4*)Ws)[t] = Wsrc[t];
    __syncthreads();
    #pragma unroll 4
    for (int k = 0; k < KC; ++k) {
      float wv[TN], av[TM];
      #pragma unroll
      for (int n = 0; n < TN; ++n) wv[n] = Ws[k * NOUT + tx * TN + n];
      #pragma unroll
      for (int m = 0; m < TM; ++m) av[m] = As[ty * TM + m][k];
      #pragma unroll
      for (int m = 0; m < TM; ++m)
        #pragma unroll
        for (int n = 0; n < TN; ++n) acc[m][n] = fmaf(av[m], wv[n], acc[m][n]);
    }
    __syncthreads();
  }
  #pragma unroll
  for (int m = 0; m < TM; ++m) {
    int gr = row0 + ty * TM + m;
    if (gr < N) {
      float s = dis ? dis[gr] : 1.f;
      #pragma unroll
      for (int n = 0; n < TN; ++n)
        C[(size_t)gr * ldc + tx * TN + n] = acc[m][n] * s;
    }
  }
}

// ---------------- aggregation: out[v] = dis[v]*(g[v] + sum_in g[u]) + b ----------------
template<int D, bool RELU, bool LOGSM>
__launch_bounds__(BLK)
__global__ void k_agg(const float* __restrict__ g, int ldg,
                      const float* __restrict__ dis, const float* __restrict__ bias,
                      const int* __restrict__ offs, const int* __restrict__ csr,
                      float* __restrict__ dst, int ldd, int N) {
  int wid = (blockIdx.x * BLK + threadIdx.x) >> 6;   // one wave per node
  int lane = threadIdx.x & 63;
  if (wid >= N) return;
  float acc0 = 0.f, acc1 = 0.f;
  if constexpr (D == 128) {
    float2 s = *(const float2*)&g[(size_t)wid * ldg + lane * 2];
    acc0 = s.x; acc1 = s.y;
  } else {
    if (lane < D) acc0 = g[(size_t)wid * ldg + lane];
  }
  int beg = offs[wid], end = offs[wid + 1];
  for (int e0 = beg; e0 < end; e0 += 64) {
    int cnt = end - e0; if (cnt > 64) cnt = 64;
    int u = (lane < cnt) ? csr[e0 + lane] : 0;
    for (int j = 0; j < cnt; ++j) {
      int uu = __shfl(u, j);
      if constexpr (D == 128) {
        float2 v = *(const float2*)&g[(size_t)uu * ldg + lane * 2];
        acc0 += v.x; acc1 += v.y;
      } else {
        if (lane < D) acc0 += g[(size_t)uu * ldg + lane];
      }
    }
  }
  float dv = dis[wid];
  if constexpr (D == 128) {
    float2 o;
    o.x = dv * acc0 + bias[lane * 2];
    o.y = dv * acc1 + bias[lane * 2 + 1];
    if constexpr (RELU) { o.x = fmaxf(o.x, 0.f); o.y = fmaxf(o.y, 0.f); }
    *(float2*)&dst[(size_t)wid * ldd + lane * 2] = o;
  } else {
    float o = 0.f;
    if (lane < D) o = dv * acc0 + bias[lane];
    if constexpr (RELU) o = fmaxf(o, 0.f);
    if constexpr (LOGSM) {
      float v = (lane < D) ? o : -__builtin_inff();
      float m = v;
      #pragma unroll
      for (int s = 32; s >= 1; s >>= 1) m = fmaxf(m, __shfl_xor(m, s));
      float ex = (lane < D) ? expf(v - m) : 0.f;
      float sum = ex;
      #pragma unroll
      for (int s = 32; s >= 1; s >>= 1) sum += __shfl_xor(sum, s);
      o = v - m - logf(sum);
    }
    if (lane < D) dst[(size_t)wid * ldd + lane] = o;
  }
}

// ---------------- launcher ----------------
extern "C" void kernel_launch(void* const* d_in, const int* in_sizes, int n_in,
                              void* d_out, int out_size, void* d_ws, size_t ws_size,
                              hipStream_t stream) {
  const float* x    = (const float*)d_in[0];
  const int*   ei   = (const int*)d_in[1];
  const float* eig  = (const float*)d_in[2];
  const float* W1   = (const float*)d_in[3];
  const float* b1   = (const float*)d_in[4];
  const float* W2   = (const float*)d_in[5];
  const float* b2   = (const float*)d_in[6];
  const float* linW = (const float*)d_in[7];
  const float* W3   = (const float*)d_in[8];
  const float* b3   = (const float*)d_in[9];
  float* out = (float*)d_out;

  const int N = in_sizes[0] / 512;
  const int E = in_sizes[1] / 2;

  char* ws = (char*)d_ws;
  size_t off = 0;
  auto alloc = [&](size_t bytes) { char* p = ws + off; off = ws_align(off + bytes); return p; };
  int*   rowA   = (int*)alloc((size_t)E * 4);
  int*   colA   = (int*)alloc((size_t)E * 4);
  int*   csr    = (int*)alloc((size_t)E * 4);
  int*   deg    = (int*)alloc((size_t)N * 4);
  int*   offs   = (int*)alloc((size_t)(N + 1) * 4);
  int*   cursor = (int*)alloc((size_t)N * 4);
  int*   bsum   = (int*)alloc(4096);
  int*   flag   = (int*)alloc(256);
  float* dis    = (float*)alloc((size_t)N * 4);
  float* F      = (float*)alloc((size_t)N * 128 * 4);   // g buffers (max 128 cols)
  float* G      = (float*)alloc((size_t)N * 128 * 4);   // h1 then hcat

  hipMemsetAsync(deg, 0, (size_t)N * 4, stream);
  hipMemsetAsync(cursor, 0, (size_t)N * 4, stream);

  const int gE = (E + BLK - 1) / BLK;
  const int gN = (N + BLK - 1) / BLK;

  k_detect<<<1, 1, 0, stream>>>(ei, flag);
  k_convert<<<gE, BLK, 0, stream>>>(ei, flag, rowA, colA, E);
  k_deg<<<gE, BLK, 0, stream>>>(colA, deg, E);
  k_dis<<<gN, BLK, 0, stream>>>(deg, dis, N);
  k_scan1<<<gN, BLK, 0, stream>>>(deg, offs, bsum, N);
  k_scan2<<<1, BLK, 0, stream>>>(bsum, gN);
  k_scan3<<<gN, BLK, 0, stream>>>(offs, bsum, N, E);
  k_scatter<<<gE, BLK, 0, stream>>>(rowA, colA, offs, cursor, csr, E);

  const int gG = (N + 63) / 64;       // GEMM blocks (BM=64)
  const int gA = (N + 3) / 4;         // agg blocks (4 waves/block)

  // conv1: g1 = (x @ W1)*dis ; h1 = relu(dis*(g1[v]+sum) + b1)
  k_gemm<512, 128, 8, 4, 64><<<gG, BLK, 0, stream>>>(x, W1, dis, F, 128, N);
  k_agg<128, true, false><<<gA, BLK, 0, stream>>>(F, 128, dis, b1, offs, csr, G, 128, N);
  // conv2: g2 = (h1 @ W2)*dis ; then spectral xp into right half of hcat (=G)
  k_gemm<128, 64, 4, 4, 64><<<gG, BLK, 0, stream>>>(G, W2, dis, F, 64, N);
  k_gemm<128, 64, 4, 4, 64><<<gG, BLK, 0, stream>>>(eig, linW, nullptr, G + 64, 128, N);
  k_agg<64, true, false><<<gA, BLK, 0, stream>>>(F, 64, dis, b2, offs, csr, G, 128, N);
  // conv3: g3 = (hcat @ W3)*dis ; out = log_softmax(dis*(g3[v]+sum)+b3)
  k_gemm<128, 40, 2, 5, 64><<<gG, BLK, 0, stream>>>(G, W3, dis, F, 40, N);
  k_agg<40, false, true><<<gA, BLK, 0, stream>>>(F, 40, dis, b3, offs, csr, out, 40, N);
}

// Round 2
// 533.914 us; speedup vs baseline: 1.2625x; 1.2625x over previous
//
#include <hip/hip_runtime.h>
#include <cstdint>
#include <cstddef>

constexpr int BLK = 256;

static inline size_t ws_align(size_t x) { return (x + 255) & ~size_t(255); }

typedef __attribute__((ext_vector_type(8))) short bf16x8;
typedef __attribute__((ext_vector_type(4))) float f32x4;

__device__ inline unsigned short f2bf(float f) {
  unsigned int u = __float_as_uint(f);
  unsigned int r = (u + 0x7fffu + ((u >> 16) & 1u)) >> 16;   // RNE
  return (unsigned short)r;
}

// ---------------- edge layout detect & convert ----------------
__global__ void k_detect(const int* __restrict__ ei, int* __restrict__ flag) {
  int allz = 1;
  for (int i = 0; i < 32; ++i) allz &= (ei[2 * i + 1] == 0) ? 1 : 0;
  flag[0] = allz;
}

__global__ void k_convert(const int* __restrict__ ei, const int* __restrict__ flag,
                          int* __restrict__ row, int* __restrict__ col, int E) {
  int i = blockIdx.x * BLK + threadIdx.x;
  if (i >= E) return;
  if (flag[0]) { row[i] = ei[2 * i]; col[i] = ei[2 * (E + i)]; }
  else         { row[i] = ei[i];     col[i] = ei[E + i]; }
}

// ---------------- degree, dis, scan, scatter (CSR build) ----------------
__global__ void k_deg(const int* __restrict__ col, int* __restrict__ deg, int E) {
  int i = blockIdx.x * BLK + threadIdx.x;
  if (i < E) atomicAdd(&deg[col[i]], 1);
}

__global__ void k_dis(const int* __restrict__ deg, float* __restrict__ dis, int n) {
  int i = blockIdx.x * BLK + threadIdx.x;
  if (i < n) dis[i] = 1.0f / sqrtf((float)(deg[i] + 1));
}

__global__ void k_scan1(const int* __restrict__ deg, int* __restrict__ offs,
                        int* __restrict__ bsum, int n) {
  __shared__ int wsums[5];
  int i = blockIdx.x * BLK + threadIdx.x;
  int v = (i < n) ? deg[i] : 0;
  int lane = threadIdx.x & 63, w = threadIdx.x >> 6;
  int x = v;
  #pragma unroll
  for (int s = 1; s < 64; s <<= 1) { int t = __shfl_up(x, s); if (lane >= s) x += t; }
  if (lane == 63) wsums[w] = x;
  __syncthreads();
  if (threadIdx.x == 0) {
    int a = 0;
    for (int k = 0; k < 4; ++k) { int t = wsums[k]; wsums[k] = a; a += t; }
    wsums[4] = a;
  }
  __syncthreads();
  int incl = x + wsums[w];
  if (i < n) offs[i] = incl - v;
  if (threadIdx.x == 0) bsum[blockIdx.x] = wsums[4];
}

__global__ void k_scan2(int* __restrict__ bsum, int nb) {
  __shared__ int wsums[5];
  int v = (threadIdx.x < nb) ? bsum[threadIdx.x] : 0;
  int lane = threadIdx.x & 63, w = threadIdx.x >> 6;
  int x = v;
  #pragma unroll
  for (int s = 1; s < 64; s <<= 1) { int t = __shfl_up(x, s); if (lane >= s) x += t; }
  if (lane == 63) wsums[w] = x;
  __syncthreads();
  if (threadIdx.x == 0) {
    int a = 0;
    for (int k = 0; k < 4; ++k) { int t = wsums[k]; wsums[k] = a; a += t; }
    wsums[4] = a;
  }
  __syncthreads();
  int incl = x + wsums[w];
  if (threadIdx.x < nb) bsum[threadIdx.x] = incl - v;
}

__global__ void k_scan3(int* __restrict__ offs, const int* __restrict__ bsum,
                        int n, int E) {
  int i = blockIdx.x * BLK + threadIdx.x;
  if (i < n) offs[i] += bsum[i >> 8];
  if (i == 0) offs[n] = E;
}

__global__ void k_scatter(const int* __restrict__ row, const int* __restrict__ col,
                          const int* __restrict__ offs, int* __restrict__ cursor,
                          int* __restrict__ csr, int E) {
  int i = blockIdx.x * BLK + threadIdx.x;
  if (i >= E) return;
  int v = col[i];
  int p = atomicAdd(&cursor[v], 1);
  csr[offs[v] + p] = row[i];
}

// ---------------- W (K x NOUT fp32) -> WT (NOUTP x K bf16, zero-padded) ----------------
template<int K, int NOUT, int NOUTP>
__global__ void k_wt(const float* __restrict__ W, unsigned short* __restrict__ WT) {
  int i = blockIdx.x * BLK + threadIdx.x;
  if (i >= NOUTP * K) return;
  int n = i / K, k = i % K;
  float v = (n < NOUT) ? W[(size_t)k * NOUT + n] : 0.f;
  WT[i] = f2bf(v);
}

// ---------------- MFMA GEMM: C[i][j] = (sum_k A[i][k]*W[k][j]) * (dis?dis[i]:1) ----------------
// A: [N][K] fp32 (row stride == K), WT: [NT*16][K] bf16 row-major.
// Block = 256 threads = 4 waves; each wave computes a 16 x (NT*16) tile.
template<int K, int NT>
__launch_bounds__(256)
__global__ void k_mgemm(const float* __restrict__ A, const unsigned short* __restrict__ WT,
                        const float* __restrict__ dis, float* __restrict__ C,
                        int ldc, int NOUT, int N) {
  const int tid = threadIdx.x;
  const int lane = tid & 63;
  const int wv = tid >> 6;
  const int m = lane & 15;          // operand outer index
  const int kq = lane >> 4;         // 0..3 (k-quad)
  const int orow = blockIdx.x * 64 + wv * 16;
  int row = orow + m;
  int rowc = row < N ? row : N - 1;                 // clamp loads; store is guarded
  const float* Arow = A + (size_t)rowc * K + kq * 8;

  f32x4 acc[NT];
  #pragma unroll
  for (int t = 0; t < NT; ++t) acc[t] = {0.f, 0.f, 0.f, 0.f};

  for (int k0 = 0; k0 < K; k0 += 32) {
    float4 a0 = *(const float4*)(Arow + k0);
    float4 a1 = *(const float4*)(Arow + k0 + 4);
    bf16x8 af;
    af[0] = (short)f2bf(a0.x); af[1] = (short)f2bf(a0.y);
    af[2] = (short)f2bf(a0.z); af[3] = (short)f2bf(a0.w);
    af[4] = (short)f2bf(a1.x); af[5] = (short)f2bf(a1.y);
    af[6] = (short)f2bf(a1.z); af[7] = (short)f2bf(a1.w);
    #pragma unroll
    for (int t = 0; t < NT; ++t) {
      const unsigned short* wp = WT + (size_t)(t * 16 + m) * K + k0 + kq * 8;
      bf16x8 bf = *(const bf16x8*)wp;
      acc[t] = __builtin_amdgcn_mfma_f32_16x16x32_bf16(af, bf, acc[t], 0, 0, 0);
    }
  }
  // C/D layout: col = lane&15 (=m), row = kq*4 + r
  #pragma unroll
  for (int t = 0; t < NT; ++t) {
    #pragma unroll
    for (int r = 0; r < 4; ++r) {
      int rr = orow + kq * 4 + r;
      int cc = t * 16 + m;
      if (rr < N && cc < NOUT) {
        float s = dis ? dis[rr] : 1.f;
        C[(size_t)rr * ldc + cc] = acc[t][r] * s;
      }
    }
  }
}

// ---------------- aggregation: out[v] = dis[v]*(g[v] + sum_in g[u]) + b ----------------
template<int D, bool RELU, bool LOGSM>
__launch_bounds__(BLK)
__global__ void k_agg(const float* __restrict__ g, int ldg,
                      const float* __restrict__ dis, const float* __restrict__ bias,
                      const int* __restrict__ offs, const int* __restrict__ csr,
                      float* __restrict__ dst, int ldd, int N) {
  int wid = (blockIdx.x * BLK + threadIdx.x) >> 6;
  int lane = threadIdx.x & 63;
  if (wid >= N) return;
  float acc0 = 0.f, acc1 = 0.f;
  if constexpr (D == 128) {
    float2 s = *(const float2*)&g[(size_t)wid * ldg + lane * 2];
    acc0 = s.x; acc1 = s.y;
  } else {
    if (lane < D) acc0 = g[(size_t)wid * ldg + lane];
  }
  int beg = offs[wid], end = offs[wid + 1];
  for (int e0 = beg; e0 < end; e0 += 64) {
    int cnt = end - e0; if (cnt > 64) cnt = 64;
    int u = (lane < cnt) ? csr[e0 + lane] : 0;
    int j = 0;
    for (; j + 1 < cnt; j += 2) {
      int u0 = __shfl(u, j), u1 = __shfl(u, j + 1);
      if constexpr (D == 128) {
        float2 v0 = *(const float2*)&g[(size_t)u0 * ldg + lane * 2];
        float2 v1 = *(const float2*)&g[(size_t)u1 * ldg + lane * 2];
        acc0 += v0.x + v1.x; acc1 += v0.y + v1.y;
      } else {
        float v0 = 0.f, v1 = 0.f;
        if (lane < D) { v0 = g[(size_t)u0 * ldg + lane]; v1 = g[(size_t)u1 * ldg + lane]; }
        acc0 += v0 + v1;
      }
    }
    if (j < cnt) {
      int u0 = __shfl(u, j);
      if constexpr (D == 128) {
        float2 v0 = *(const float2*)&g[(size_t)u0 * ldg + lane * 2];
        acc0 += v0.x; acc1 += v0.y;
      } else {
        if (lane < D) acc0 += g[(size_t)u0 * ldg + lane];
      }
    }
  }
  float dv = dis[wid];
  if constexpr (D == 128) {
    float2 o;
    o.x = dv * acc0 + bias[lane * 2];
    o.y = dv * acc1 + bias[lane * 2 + 1];
    if constexpr (RELU) { o.x = fmaxf(o.x, 0.f); o.y = fmaxf(o.y, 0.f); }
    *(float2*)&dst[(size_t)wid * ldd + lane * 2] = o;
  } else {
    float o = 0.f;
    if (lane < D) o = dv * acc0 + bias[lane];
    if constexpr (RELU) o = fmaxf(o, 0.f);
    if constexpr (LOGSM) {
      float v = (lane < D) ? o : -__builtin_inff();
      float mx = v;
      #pragma unroll
      for (int s = 32; s >= 1; s >>= 1) mx = fmaxf(mx, __shfl_xor(mx, s));
      float ex = (lane < D) ? expf(v - mx) : 0.f;
      float sum = ex;
      #pragma unroll
      for (int s = 32; s >= 1; s >>= 1) sum += __shfl_xor(sum, s);
      o = v - mx - logf(sum);
    }
    if (lane < D) dst[(size_t)wid * ldd + lane] = o;
  }
}

// ---------------- launcher ----------------
extern "C" void kernel_launch(void* const* d_in, const int* in_sizes, int n_in,
                              void* d_out, int out_size, void* d_ws, size_t ws_size,
                              hipStream_t stream) {
  const float* x    = (const float*)d_in[0];
  const int*   ei   = (const int*)d_in[1];
  const float* eig  = (const float*)d_in[2];
  const float* W1   = (const float*)d_in[3];
  const float* b1   = (const float*)d_in[4];
  const float* W2   = (const float*)d_in[5];
  const float* b2   = (const float*)d_in[6];
  const float* linW = (const float*)d_in[7];
  const float* W3   = (const float*)d_in[8];
  const float* b3   = (const float*)d_in[9];
  float* out = (float*)d_out;

  const int N = in_sizes[0] / 512;
  const int E = in_sizes[1] / 2;

  char* ws = (char*)d_ws;
  size_t off = 0;
  auto alloc = [&](size_t bytes) { char* p = ws + off; off = ws_align(off + bytes); return p; };
  int*   rowA   = (int*)alloc((size_t)E * 4);
  int*   colA   = (int*)alloc((size_t)E * 4);
  int*   csr    = (int*)alloc((size_t)E * 4);
  int*   deg    = (int*)alloc((size_t)N * 4);
  int*   offs   = (int*)alloc((size_t)(N + 1) * 4);
  int*   cursor = (int*)alloc((size_t)N * 4);
  int*   bsum   = (int*)alloc(4096);
  int*   flag   = (int*)alloc(256);
  float* dis    = (float*)alloc((size_t)N * 4);
  float* F      = (float*)alloc((size_t)N * 128 * 4);   // conv GEMM outputs (max 128 cols)
  float* G      = (float*)alloc((size_t)N * 128 * 4);   // h1 then hcat
  unsigned short* WT1 = (unsigned short*)alloc(128 * 512 * 2);
  unsigned short* WT2 = (unsigned short*)alloc(64 * 128 * 2);
  unsigned short* WTl = (unsigned short*)alloc(64 * 128 * 2);
  unsigned short* WT3 = (unsigned short*)alloc(48 * 128 * 2);

  hipMemsetAsync(deg, 0, (size_t)N * 4, stream);
  hipMemsetAsync(cursor, 0, (size_t)N * 4, stream);

  const int gE = (E + BLK - 1) / BLK;
  const int gN = (N + BLK - 1) / BLK;

  k_detect<<<1, 1, 0, stream>>>(ei, flag);
  k_convert<<<gE, BLK, 0, stream>>>(ei, flag, rowA, colA, E);
  k_deg<<<gE, BLK, 0, stream>>>(colA, deg, E);
  k_dis<<<gN, BLK, 0, stream>>>(deg, dis, N);
  k_scan1<<<gN, BLK, 0, stream>>>(deg, offs, bsum, N);
  k_scan2<<<1, BLK, 0, stream>>>(bsum, gN);
  k_scan3<<<gN, BLK, 0, stream>>>(offs, bsum, N, E);
  k_scatter<<<gE, BLK, 0, stream>>>(rowA, colA, offs, cursor, csr, E);

  // weight conversions (tiny)
  k_wt<512, 128, 128><<<(128 * 512 + BLK - 1) / BLK, BLK, 0, stream>>>(W1, WT1);
  k_wt<128, 64, 64><<<(64 * 128 + BLK - 1) / BLK, BLK, 0, stream>>>(W2, WT2);
  k_wt<128, 64, 64><<<(64 * 128 + BLK - 1) / BLK, BLK, 0, stream>>>(linW, WTl);
  k_wt<128, 40, 48><<<(48 * 128 + BLK - 1) / BLK, BLK, 0, stream>>>(W3, WT3);

  const int gG = (N + 63) / 64;       // MFMA GEMM blocks (BM=64)
  const int gA = (N + 3) / 4;         // agg blocks (4 waves/block)

  // conv1: g1 = (x @ W1)*dis ; h1 = relu(dis*(g1[v]+sum) + b1)
  k_mgemm<512, 8><<<gG, BLK, 0, stream>>>(x, WT1, dis, F, 128, 128, N);
  k_agg<128, true, false><<<gA, BLK, 0, stream>>>(F, 128, dis, b1, offs, csr, G, 128, N);
  // conv2: g2 = (h1 @ W2)*dis ; spectral xp = eig @ linW into right half of G
  k_mgemm<128, 4><<<gG, BLK, 0, stream>>>(G, WT2, dis, F, 64, 64, N);
  k_mgemm<128, 4><<<gG, BLK, 0, stream>>>(eig, WTl, nullptr, G + 64, 128, 64, N);
  k_agg<64, true, false><<<gA, BLK, 0, stream>>>(F, 64, dis, b2, offs, csr, G, 128, N);
  // conv3: g3 = (hcat @ W3)*dis ; out = log_softmax(dis*(g3[v]+sum)+b3)
  k_mgemm<128, 3><<<gG, BLK, 0, stream>>>(G, WT3, dis, F, 40, 40, N);
  k_agg<40, false, true><<<gA, BLK, 0, stream>>>(F, 40, dis, b3, offs, csr, out, 40, N);
}

// Round 3
// 451.693 us; speedup vs baseline: 1.4923x; 1.1820x over previous
//
#include <hip/hip_runtime.h>
#include <cstdint>
#include <cstddef>

constexpr int BLK = 256;

static inline size_t ws_align(size_t x) { return (x + 255) & ~size_t(255); }

typedef __attribute__((ext_vector_type(8))) short bf16x8;
typedef __attribute__((ext_vector_type(4))) float f32x4;

__device__ inline unsigned short f2bf(float f) {
  unsigned int u = __float_as_uint(f);
  unsigned int r = (u + 0x7fffu + ((u >> 16) & 1u)) >> 16;   // RNE
  return (unsigned short)r;
}
__device__ inline float bf2f(unsigned short u) {
  return __uint_as_float(((unsigned int)u) << 16);
}
__device__ inline float bf2f_lo(unsigned int w) {            // low bf16 of packed pair
  return __uint_as_float(w << 16);
}
__device__ inline float bf2f_hi(unsigned int w) {            // high bf16 of packed pair
  return __uint_as_float(w & 0xffff0000u);
}

// ---------------- edge layout detect & convert ----------------
__global__ void k_detect(const int* __restrict__ ei, int* __restrict__ flag) {
  int allz = 1;
  for (int i = 0; i < 32; ++i) allz &= (ei[2 * i + 1] == 0) ? 1 : 0;
  flag[0] = allz;
}

__global__ void k_convert(const int* __restrict__ ei, const int* __restrict__ flag,
                          int* __restrict__ row, int* __restrict__ col, int E) {
  int i = blockIdx.x * BLK + threadIdx.x;
  if (i >= E) return;
  if (flag[0]) { row[i] = ei[2 * i]; col[i] = ei[2 * (E + i)]; }
  else         { row[i] = ei[i];     col[i] = ei[E + i]; }
}

// ---------------- degree, dis, scan, scatter (CSR build) ----------------
__global__ void k_deg(const int* __restrict__ col, int* __restrict__ deg, int E) {
  int i = blockIdx.x * BLK + threadIdx.x;
  if (i < E) atomicAdd(&deg[col[i]], 1);
}

__global__ void k_dis(const int* __restrict__ deg, float* __restrict__ dis, int n) {
  int i = blockIdx.x * BLK + threadIdx.x;
  if (i < n) dis[i] = 1.0f / sqrtf((float)(deg[i] + 1));
}

__global__ void k_scan1(const int* __restrict__ deg, int* __restrict__ offs,
                        int* __restrict__ bsum, int n) {
  __shared__ int wsums[5];
  int i = blockIdx.x * BLK + threadIdx.x;
  int v = (i < n) ? deg[i] : 0;
  int lane = threadIdx.x & 63, w = threadIdx.x >> 6;
  int x = v;
  #pragma unroll
  for (int s = 1; s < 64; s <<= 1) { int t = __shfl_up(x, s); if (lane >= s) x += t; }
  if (lane == 63) wsums[w] = x;
  __syncthreads();
  if (threadIdx.x == 0) {
    int a = 0;
    for (int k = 0; k < 4; ++k) { int t = wsums[k]; wsums[k] = a; a += t; }
    wsums[4] = a;
  }
  __syncthreads();
  int incl = x + wsums[w];
  if (i < n) offs[i] = incl - v;
  if (threadIdx.x == 0) bsum[blockIdx.x] = wsums[4];
}

__global__ void k_scan2(int* __restrict__ bsum, int nb) {
  __shared__ int wsums[5];
  int v = (threadIdx.x < nb) ? bsum[threadIdx.x] : 0;
  int lane = threadIdx.x & 63, w = threadIdx.x >> 6;
  int x = v;
  #pragma unroll
  for (int s = 1; s < 64; s <<= 1) { int t = __shfl_up(x, s); if (lane >= s) x += t; }
  if (lane == 63) wsums[w] = x;
  __syncthreads();
  if (threadIdx.x == 0) {
    int a = 0;
    for (int k = 0; k < 4; ++k) { int t = wsums[k]; wsums[k] = a; a += t; }
    wsums[4] = a;
  }
  __syncthreads();
  int incl = x + wsums[w];
  if (threadIdx.x < nb) bsum[threadIdx.x] = incl - v;
}

__global__ void k_scan3(int* __restrict__ offs, const int* __restrict__ bsum,
                        int n, int E) {
  int i = blockIdx.x * BLK + threadIdx.x;
  if (i < n) offs[i] += bsum[i >> 8];
  if (i == 0) offs[n] = E;
}

__global__ void k_scatter(const int* __restrict__ row, const int* __restrict__ col,
                          const int* __restrict__ offs, int* __restrict__ cursor,
                          int* __restrict__ csr, int E) {
  int i = blockIdx.x * BLK + threadIdx.x;
  if (i >= E) return;
  int v = col[i];
  int p = atomicAdd(&cursor[v], 1);
  csr[offs[v] + p] = row[i];
}

// ---------------- W (K x NOUT fp32) -> WT (NOUTP x K bf16, zero-padded) ----------------
template<int K, int NOUT, int NOUTP>
__global__ void k_wt(const float* __restrict__ W, unsigned short* __restrict__ WT) {
  int i = blockIdx.x * BLK + threadIdx.x;
  if (i >= NOUTP * K) return;
  int n = i / K, k = i % K;
  float v = (n < NOUT) ? W[(size_t)k * NOUT + n] : 0.f;
  WT[i] = f2bf(v);
}

// ---------------- MFMA GEMM: C[i][j] = (sum_k A[i][k]*W[k][j]) * (dis?dis[i]:1) ----------------
// A: [N][K] (fp32 if AF32 else bf16), row stride == K. WT: [NT*16][K] bf16 row-major.
// C: bf16, row stride ldc. Block = 256 threads = 4 waves; wave computes 16 x (NT*16).
template<int K, int NT, bool AF32>
__launch_bounds__(256)
__global__ void k_mgemm(const void* __restrict__ Av, const unsigned short* __restrict__ WT,
                        const float* __restrict__ dis, unsigned short* __restrict__ C,
                        int ldc, int NOUT, int N) {
  const int tid = threadIdx.x;
  const int lane = tid & 63;
  const int wv = tid >> 6;
  const int m = lane & 15;          // operand outer index
  const int kq = lane >> 4;         // 0..3 (k-quad)
  const int orow = blockIdx.x * 64 + wv * 16;
  int row = orow + m;
  int rowc = row < N ? row : N - 1;                 // clamp loads; store is guarded

  f32x4 acc[NT];
  #pragma unroll
  for (int t = 0; t < NT; ++t) acc[t] = {0.f, 0.f, 0.f, 0.f};

  for (int k0 = 0; k0 < K; k0 += 32) {
    bf16x8 af;
    if constexpr (AF32) {
      const float* Arow = (const float*)Av + (size_t)rowc * K + kq * 8 + k0;
      float4 a0 = *(const float4*)Arow;
      float4 a1 = *(const float4*)(Arow + 4);
      af[0] = (short)f2bf(a0.x); af[1] = (short)f2bf(a0.y);
      af[2] = (short)f2bf(a0.z); af[3] = (short)f2bf(a0.w);
      af[4] = (short)f2bf(a1.x); af[5] = (short)f2bf(a1.y);
      af[6] = (short)f2bf(a1.z); af[7] = (short)f2bf(a1.w);
    } else {
      const unsigned short* Arow = (const unsigned short*)Av + (size_t)rowc * K + kq * 8 + k0;
      af = *(const bf16x8*)Arow;
    }
    #pragma unroll
    for (int t = 0; t < NT; ++t) {
      const unsigned short* wp = WT + (size_t)(t * 16 + m) * K + k0 + kq * 8;
      bf16x8 bf = *(const bf16x8*)wp;
      acc[t] = __builtin_amdgcn_mfma_f32_16x16x32_bf16(af, bf, acc[t], 0, 0, 0);
    }
  }
  // C/D layout: col = lane&15 (=m), row = kq*4 + r
  #pragma unroll
  for (int t = 0; t < NT; ++t) {
    #pragma unroll
    for (int r = 0; r < 4; ++r) {
      int rr = orow + kq * 4 + r;
      int cc = t * 16 + m;
      if (rr < N && cc < NOUT) {
        float s = dis ? dis[rr] : 1.f;
        C[(size_t)rr * ldc + cc] = f2bf(acc[t][r] * s);
      }
    }
  }
}

// ---------------- aggregation: out[v] = dis[v]*(g[v] + sum_in g[u]) + b ----------------
// g is bf16 [N][ldg]. dst: bf16 (intermediate) or fp32 (final, with log-softmax).
template<int D, bool RELU, bool LOGSM, bool OUTF32>
__launch_bounds__(BLK)
__global__ void k_agg(const unsigned short* __restrict__ g, int ldg,
                      const float* __restrict__ dis, const float* __restrict__ bias,
                      const int* __restrict__ offs, const int* __restrict__ csr,
                      void* __restrict__ dstv, int ldd, int N) {
  int wid = (blockIdx.x * BLK + threadIdx.x) >> 6;
  int lane = threadIdx.x & 63;
  if (wid >= N) return;
  float acc0 = 0.f, acc1 = 0.f;
  if constexpr (D == 128) {
    unsigned int w = *(const unsigned int*)&g[(size_t)wid * ldg + lane * 2];
    acc0 = bf2f_lo(w); acc1 = bf2f_hi(w);
  } else {
    if (lane < D) acc0 = bf2f(g[(size_t)wid * ldg + lane]);
  }
  int beg = offs[wid], end = offs[wid + 1];
  for (int e0 = beg; e0 < end; e0 += 64) {
    int cnt = end - e0; if (cnt > 64) cnt = 64;
    int u = (lane < cnt) ? csr[e0 + lane] : 0;
    int j = 0;
    for (; j + 3 < cnt; j += 4) {
      int u0 = __shfl(u, j), u1 = __shfl(u, j + 1);
      int u2 = __shfl(u, j + 2), u3 = __shfl(u, j + 3);
      if constexpr (D == 128) {
        unsigned int w0 = *(const unsigned int*)&g[(size_t)u0 * ldg + lane * 2];
        unsigned int w1 = *(const unsigned int*)&g[(size_t)u1 * ldg + lane * 2];
        unsigned int w2 = *(const unsigned int*)&g[(size_t)u2 * ldg + lane * 2];
        unsigned int w3 = *(const unsigned int*)&g[(size_t)u3 * ldg + lane * 2];
        acc0 += bf2f_lo(w0) + bf2f_lo(w1) + bf2f_lo(w2) + bf2f_lo(w3);
        acc1 += bf2f_hi(w0) + bf2f_hi(w1) + bf2f_hi(w2) + bf2f_hi(w3);
      } else {
        if (lane < D) {
          float v0 = bf2f(g[(size_t)u0 * ldg + lane]);
          float v1 = bf2f(g[(size_t)u1 * ldg + lane]);
          float v2 = bf2f(g[(size_t)u2 * ldg + lane]);
          float v3 = bf2f(g[(size_t)u3 * ldg + lane]);
          acc0 += (v0 + v1) + (v2 + v3);
        }
      }
    }
    for (; j < cnt; ++j) {
      int u0 = __shfl(u, j);
      if constexpr (D == 128) {
        unsigned int w0 = *(const unsigned int*)&g[(size_t)u0 * ldg + lane * 2];
        acc0 += bf2f_lo(w0); acc1 += bf2f_hi(w0);
      } else {
        if (lane < D) acc0 += bf2f(g[(size_t)u0 * ldg + lane]);
      }
    }
  }
  float dv = dis[wid];
  if constexpr (D == 128) {
    float ox = dv * acc0 + bias[lane * 2];
    float oy = dv * acc1 + bias[lane * 2 + 1];
    if constexpr (RELU) { ox = fmaxf(ox, 0.f); oy = fmaxf(oy, 0.f); }
    unsigned int pw = (unsigned int)f2bf(ox) | ((unsigned int)f2bf(oy) << 16);
    *(unsigned int*)&((unsigned short*)dstv)[(size_t)wid * ldd + lane * 2] = pw;
  } else {
    float o = 0.f;
    if (lane < D) o = dv * acc0 + bias[lane];
    if constexpr (RELU) o = fmaxf(o, 0.f);
    if constexpr (LOGSM) {
      float v = (lane < D) ? o : -__builtin_inff();
      float mx = v;
      #pragma unroll
      for (int s = 32; s >= 1; s >>= 1) mx = fmaxf(mx, __shfl_xor(mx, s));
      float ex = (lane < D) ? expf(v - mx) : 0.f;
      float sum = ex;
      #pragma unroll
      for (int s = 32; s >= 1; s >>= 1) sum += __shfl_xor(sum, s);
      o = v - mx - logf(sum);
    }
    if (lane < D) {
      if constexpr (OUTF32) ((float*)dstv)[(size_t)wid * ldd + lane] = o;
      else ((unsigned short*)dstv)[(size_t)wid * ldd + lane] = f2bf(o);
    }
  }
}

// ---------------- launcher ----------------
extern "C" void kernel_launch(void* const* d_in, const int* in_sizes, int n_in,
                              void* d_out, int out_size, void* d_ws, size_t ws_size,
                              hipStream_t stream) {
  const float* x    = (const float*)d_in[0];
  const int*   ei   = (const int*)d_in[1];
  const float* eig  = (const float*)d_in[2];
  const float* W1   = (const float*)d_in[3];
  const float* b1   = (const float*)d_in[4];
  const float* W2   = (const float*)d_in[5];
  const float* b2   = (const float*)d_in[6];
  const float* linW = (const float*)d_in[7];
  const float* W3   = (const float*)d_in[8];
  const float* b3   = (const float*)d_in[9];
  float* out = (float*)d_out;

  const int N = in_sizes[0] / 512;
  const int E = in_sizes[1] / 2;

  char* ws = (char*)d_ws;
  size_t off = 0;
  auto alloc = [&](size_t bytes) { char* p = ws + off; off = ws_align(off + bytes); return p; };
  int*   rowA   = (int*)alloc((size_t)E * 4);
  int*   colA   = (int*)alloc((size_t)E * 4);
  int*   csr    = (int*)alloc((size_t)E * 4);
  int*   deg    = (int*)alloc((size_t)N * 4);
  int*   offs   = (int*)alloc((size_t)(N + 1) * 4);
  int*   cursor = (int*)alloc((size_t)N * 4);
  int*   bsum   = (int*)alloc(4096);
  int*   flag   = (int*)alloc(256);
  float* dis    = (float*)alloc((size_t)N * 4);
  unsigned short* F = (unsigned short*)alloc((size_t)N * 128 * 2);  // conv GEMM outputs, bf16
  unsigned short* G = (unsigned short*)alloc((size_t)N * 128 * 2);  // h1 then hcat, bf16
  unsigned short* WT1 = (unsigned short*)alloc(128 * 512 * 2);
  unsigned short* WT2 = (unsigned short*)alloc(64 * 128 * 2);
  unsigned short* WTl = (unsigned short*)alloc(64 * 128 * 2);
  unsigned short* WT3 = (unsigned short*)alloc(48 * 128 * 2);

  hipMemsetAsync(deg, 0, (size_t)N * 4, stream);
  hipMemsetAsync(cursor, 0, (size_t)N * 4, stream);

  const int gE = (E + BLK - 1) / BLK;
  const int gN = (N + BLK - 1) / BLK;

  k_detect<<<1, 1, 0, stream>>>(ei, flag);
  k_convert<<<gE, BLK, 0, stream>>>(ei, flag, rowA, colA, E);
  k_deg<<<gE, BLK, 0, stream>>>(colA, deg, E);
  k_dis<<<gN, BLK, 0, stream>>>(deg, dis, N);
  k_scan1<<<gN, BLK, 0, stream>>>(deg, offs, bsum, N);
  k_scan2<<<1, BLK, 0, stream>>>(bsum, gN);
  k_scan3<<<gN, BLK, 0, stream>>>(offs, bsum, N, E);
  k_scatter<<<gE, BLK, 0, stream>>>(rowA, colA, offs, cursor, csr, E);

  // weight conversions (tiny)
  k_wt<512, 128, 128><<<(128 * 512 + BLK - 1) / BLK, BLK, 0, stream>>>(W1, WT1);
  k_wt<128, 64, 64><<<(64 * 128 + BLK - 1) / BLK, BLK, 0, stream>>>(W2, WT2);
  k_wt<128, 64, 64><<<(64 * 128 + BLK - 1) / BLK, BLK, 0, stream>>>(linW, WTl);
  k_wt<128, 40, 48><<<(48 * 128 + BLK - 1) / BLK, BLK, 0, stream>>>(W3, WT3);

  const int gG = (N + 63) / 64;       // MFMA GEMM blocks (BM=64)
  const int gA = (N + 3) / 4;         // agg blocks (4 waves/block)

  // conv1: g1 = (x @ W1)*dis ; h1 = relu(dis*(g1[v]+sum) + b1)   [h1 -> G, bf16]
  k_mgemm<512, 8, true><<<gG, BLK, 0, stream>>>(x, WT1, dis, F, 128, 128, N);
  k_agg<128, true, false, false><<<gA, BLK, 0, stream>>>(F, 128, dis, b1, offs, csr, G, 128, N);
  // conv2: g2 = (h1 @ W2)*dis ; spectral xp = eig @ linW into right half of G
  k_mgemm<128, 4, false><<<gG, BLK, 0, stream>>>(G, WT2, dis, F, 64, 64, N);
  k_mgemm<128, 4, true><<<gG, BLK, 0, stream>>>(eig, WTl, nullptr, G + 64, 128, 64, N);
  k_agg<64, true, false, false><<<gA, BLK, 0, stream>>>(F, 64, dis, b2, offs, csr, G, 128, N);
  // conv3: g3 = (hcat @ W3)*dis ; out = log_softmax(dis*(g3[v]+sum)+b3)  [fp32 out]
  k_mgemm<128, 3, false><<<gG, BLK, 0, stream>>>(G, WT3, dis, F, 40, 40, N);
  k_agg<40, false, true, true><<<gA, BLK, 0, stream>>>(F, 40, dis, b3, offs, csr, out, 40, N);
}

// Round 4
// 408.761 us; speedup vs baseline: 1.6491x; 1.1050x over previous
//
#include <hip/hip_runtime.h>
#include <cstdint>
#include <cstddef>

constexpr int BLK = 256;

static inline size_t ws_align(size_t x) { return (x + 255) & ~size_t(255); }

typedef __attribute__((ext_vector_type(8))) short bf16x8;
typedef __attribute__((ext_vector_type(4))) float f32x4;

__device__ inline unsigned short f2bf(float f) {
  unsigned int u = __float_as_uint(f);
  unsigned int r = (u + 0x7fffu + ((u >> 16) & 1u)) >> 16;   // RNE
  return (unsigned short)r;
}
__device__ inline float bf2f(unsigned short u) {
  return __uint_as_float(((unsigned int)u) << 16);
}
__device__ inline float bf2f_lo(unsigned int w) {
  return __uint_as_float(w << 16);
}
__device__ inline float bf2f_hi(unsigned int w) {
  return __uint_as_float(w & 0xffff0000u);
}

// ---------------- edge layout detect & convert ----------------
__global__ void k_detect(const int* __restrict__ ei, int* __restrict__ flag) {
  int allz = 1;
  for (int i = 0; i < 32; ++i) allz &= (ei[2 * i + 1] == 0) ? 1 : 0;
  flag[0] = allz;
}

__global__ void k_convert(const int* __restrict__ ei, const int* __restrict__ flag,
                          int* __restrict__ row, int* __restrict__ col, int E) {
  int i = blockIdx.x * BLK + threadIdx.x;
  if (i >= E) return;
  if (flag[0]) { row[i] = ei[2 * i]; col[i] = ei[2 * (E + i)]; }
  else         { row[i] = ei[i];     col[i] = ei[E + i]; }
}

// ---------------- degree, dis, scan, scatter (CSR build) ----------------
__global__ void k_deg(const int* __restrict__ col, int* __restrict__ deg, int E) {
  int i = blockIdx.x * BLK + threadIdx.x;
  if (i < E) atomicAdd(&deg[col[i]], 1);
}

__global__ void k_dis(const int* __restrict__ deg, float* __restrict__ dis, int n) {
  int i = blockIdx.x * BLK + threadIdx.x;
  if (i < n) dis[i] = 1.0f / sqrtf((float)(deg[i] + 1));
}

__global__ void k_scan1(const int* __restrict__ deg, int* __restrict__ offs,
                        int* __restrict__ bsum, int n) {
  __shared__ int wsums[5];
  int i = blockIdx.x * BLK + threadIdx.x;
  int v = (i < n) ? deg[i] : 0;
  int lane = threadIdx.x & 63, w = threadIdx.x >> 6;
  int x = v;
  #pragma unroll
  for (int s = 1; s < 64; s <<= 1) { int t = __shfl_up(x, s); if (lane >= s) x += t; }
  if (lane == 63) wsums[w] = x;
  __syncthreads();
  if (threadIdx.x == 0) {
    int a = 0;
    for (int k = 0; k < 4; ++k) { int t = wsums[k]; wsums[k] = a; a += t; }
    wsums[4] = a;
  }
  __syncthreads();
  int incl = x + wsums[w];
  if (i < n) offs[i] = incl - v;
  if (threadIdx.x == 0) bsum[blockIdx.x] = wsums[4];
}

__global__ void k_scan2(int* __restrict__ bsum, int nb) {
  __shared__ int wsums[5];
  int v = (threadIdx.x < nb) ? bsum[threadIdx.x] : 0;
  int lane = threadIdx.x & 63, w = threadIdx.x >> 6;
  int x = v;
  #pragma unroll
  for (int s = 1; s < 64; s <<= 1) { int t = __shfl_up(x, s); if (lane >= s) x += t; }
  if (lane == 63) wsums[w] = x;
  __syncthreads();
  if (threadIdx.x == 0) {
    int a = 0;
    for (int k = 0; k < 4; ++k) { int t = wsums[k]; wsums[k] = a; a += t; }
    wsums[4] = a;
  }
  __syncthreads();
  int incl = x + wsums[w];
  if (threadIdx.x < nb) bsum[threadIdx.x] = incl - v;
}

__global__ void k_scan3(int* __restrict__ offs, const int* __restrict__ bsum,
                        int n, int E) {
  int i = blockIdx.x * BLK + threadIdx.x;
  if (i < n) offs[i] += bsum[i >> 8];
  if (i == 0) offs[n] = E;
}

__global__ void k_scatter(const int* __restrict__ row, const int* __restrict__ col,
                          const int* __restrict__ offs, int* __restrict__ cursor,
                          int* __restrict__ csr, int E) {
  int i = blockIdx.x * BLK + threadIdx.x;
  if (i >= E) return;
  int v = col[i];
  int p = atomicAdd(&cursor[v], 1);
  csr[offs[v] + p] = row[i];
}

// ---------------- W (K x NOUT fp32) -> WT (NOUTP x K bf16, zero-padded) ----------------
template<int K, int NOUT, int NOUTP>
__global__ void k_wt(const float* __restrict__ W, unsigned short* __restrict__ WT) {
  int i = blockIdx.x * BLK + threadIdx.x;
  if (i >= NOUTP * K) return;
  int n = i / K, k = i % K;
  float v = (n < NOUT) ? W[(size_t)k * NOUT + n] : 0.f;
  WT[i] = f2bf(v);
}

// ---------------- MFMA GEMM: C[i][j] = (sum_k A[i][k]*W[k][j]) * (dis?dis[i]:1) ----------------
// A: [N][K] (fp32 if AF32 else bf16), row stride == K. WT: [NT*16][K] bf16 row-major.
// C: bf16, row stride ldc. Block = 4 waves; each wave computes (MR*16) x (NT*16).
template<int K, int NT, int MR, bool AF32>
__launch_bounds__(256)
__global__ void k_mgemm(const void* __restrict__ Av, const unsigned short* __restrict__ WT,
                        const float* __restrict__ dis, unsigned short* __restrict__ C,
                        int ldc, int NOUT, int N) {
  const int tid = threadIdx.x;
  const int lane = tid & 63;
  const int wv = tid >> 6;
  const int m = lane & 15;          // operand outer index
  const int kq = lane >> 4;         // 0..3 (k-quad)
  const int orow = blockIdx.x * (64 * MR) + wv * (16 * MR);

  int rowc[MR];
  #pragma unroll
  for (int mr = 0; mr < MR; ++mr) {
    int row = orow + mr * 16 + m;
    rowc[mr] = row < N ? row : N - 1;   // clamp loads; store is guarded
  }

  f32x4 acc[MR][NT];
  #pragma unroll
  for (int mr = 0; mr < MR; ++mr)
    #pragma unroll
    for (int t = 0; t < NT; ++t) acc[mr][t] = {0.f, 0.f, 0.f, 0.f};

  #pragma unroll 2
  for (int k0 = 0; k0 < K; k0 += 32) {
    bf16x8 af[MR];
    #pragma unroll
    for (int mr = 0; mr < MR; ++mr) {
      if constexpr (AF32) {
        const float* Arow = (const float*)Av + (size_t)rowc[mr] * K + kq * 8 + k0;
        float4 a0 = *(const float4*)Arow;
        float4 a1 = *(const float4*)(Arow + 4);
        af[mr][0] = (short)f2bf(a0.x); af[mr][1] = (short)f2bf(a0.y);
        af[mr][2] = (short)f2bf(a0.z); af[mr][3] = (short)f2bf(a0.w);
        af[mr][4] = (short)f2bf(a1.x); af[mr][5] = (short)f2bf(a1.y);
        af[mr][6] = (short)f2bf(a1.z); af[mr][7] = (short)f2bf(a1.w);
      } else {
        const unsigned short* Arow = (const unsigned short*)Av + (size_t)rowc[mr] * K + kq * 8 + k0;
        af[mr] = *(const bf16x8*)Arow;
      }
    }
    bf16x8 bf[NT];
    #pragma unroll
    for (int t = 0; t < NT; ++t)
      bf[t] = *(const bf16x8*)(WT + (size_t)(t * 16 + m) * K + k0 + kq * 8);
    #pragma unroll
    for (int t = 0; t < NT; ++t)
      #pragma unroll
      for (int mr = 0; mr < MR; ++mr)
        acc[mr][t] = __builtin_amdgcn_mfma_f32_16x16x32_bf16(af[mr], bf[t], acc[mr][t], 0, 0, 0);
  }
  // C/D layout: col = lane&15 (=m), row = kq*4 + r
  #pragma unroll
  for (int mr = 0; mr < MR; ++mr) {
    #pragma unroll
    for (int r = 0; r < 4; ++r) {
      int rr = orow + mr * 16 + kq * 4 + r;
      if (rr < N) {
        float s = dis ? dis[rr] : 1.f;
        #pragma unroll
        for (int t = 0; t < NT; ++t) {
          int cc = t * 16 + m;
          if (cc < NOUT)
            C[(size_t)rr * ldc + cc] = f2bf(acc[mr][t][r] * s);
        }
      }
    }
  }
}

// ---------------- aggregation: out[v] = dis[v]*(g[v] + sum_in g[u]) + b ----------------
// g is bf16 [N][ldg]. dst: bf16 (intermediate) or fp32 (final, with log-softmax).
template<int D, bool RELU, bool LOGSM, bool OUTF32>
__launch_bounds__(BLK)
__global__ void k_agg(const unsigned short* __restrict__ g, int ldg,
                      const float* __restrict__ dis, const float* __restrict__ bias,
                      const int* __restrict__ offs, const int* __restrict__ csr,
                      void* __restrict__ dstv, int ldd, int N) {
  int wid = (blockIdx.x * BLK + threadIdx.x) >> 6;
  int lane = threadIdx.x & 63;
  if (wid >= N) return;
  float acc0 = 0.f, acc1 = 0.f;
  if constexpr (D == 128) {
    unsigned int w = *(const unsigned int*)&g[(size_t)wid * ldg + lane * 2];
    acc0 = bf2f_lo(w); acc1 = bf2f_hi(w);
  } else {
    if (lane < D) acc0 = bf2f(g[(size_t)wid * ldg + lane]);
  }
  int beg = offs[wid], end = offs[wid + 1];
  for (int e0 = beg; e0 < end; e0 += 64) {
    int cnt = end - e0; if (cnt > 64) cnt = 64;
    int u = (lane < cnt) ? csr[e0 + lane] : 0;
    int j = 0;
    for (; j + 3 < cnt; j += 4) {
      int u0 = __shfl(u, j), u1 = __shfl(u, j + 1);
      int u2 = __shfl(u, j + 2), u3 = __shfl(u, j + 3);
      if constexpr (D == 128) {
        unsigned int w0 = *(const unsigned int*)&g[(size_t)u0 * ldg + lane * 2];
        unsigned int w1 = *(const unsigned int*)&g[(size_t)u1 * ldg + lane * 2];
        unsigned int w2 = *(const unsigned int*)&g[(size_t)u2 * ldg + lane * 2];
        unsigned int w3 = *(const unsigned int*)&g[(size_t)u3 * ldg + lane * 2];
        acc0 += bf2f_lo(w0) + bf2f_lo(w1) + bf2f_lo(w2) + bf2f_lo(w3);
        acc1 += bf2f_hi(w0) + bf2f_hi(w1) + bf2f_hi(w2) + bf2f_hi(w3);
      } else {
        if (lane < D) {
          float v0 = bf2f(g[(size_t)u0 * ldg + lane]);
          float v1 = bf2f(g[(size_t)u1 * ldg + lane]);
          float v2 = bf2f(g[(size_t)u2 * ldg + lane]);
          float v3 = bf2f(g[(size_t)u3 * ldg + lane]);
          acc0 += (v0 + v1) + (v2 + v3);
        }
      }
    }
    for (; j < cnt; ++j) {
      int u0 = __shfl(u, j);
      if constexpr (D == 128) {
        unsigned int w0 = *(const unsigned int*)&g[(size_t)u0 * ldg + lane * 2];
        acc0 += bf2f_lo(w0); acc1 += bf2f_hi(w0);
      } else {
        if (lane < D) acc0 += bf2f(g[(size_t)u0 * ldg + lane]);
      }
    }
  }
  float dv = dis[wid];
  if constexpr (D == 128) {
    float ox = dv * acc0 + bias[lane * 2];
    float oy = dv * acc1 + bias[lane * 2 + 1];
    if constexpr (RELU) { ox = fmaxf(ox, 0.f); oy = fmaxf(oy, 0.f); }
    unsigned int pw = (unsigned int)f2bf(ox) | ((unsigned int)f2bf(oy) << 16);
    *(unsigned int*)&((unsigned short*)dstv)[(size_t)wid * ldd + lane * 2] = pw;
  } else {
    float o = 0.f;
    if (lane < D) o = dv * acc0 + bias[lane];
    if constexpr (RELU) o = fmaxf(o, 0.f);
    if constexpr (LOGSM) {
      float v = (lane < D) ? o : -__builtin_inff();
      float mx = v;
      #pragma unroll
      for (int s = 32; s >= 1; s >>= 1) mx = fmaxf(mx, __shfl_xor(mx, s));
      float ex = (lane < D) ? expf(v - mx) : 0.f;
      float sum = ex;
      #pragma unroll
      for (int s = 32; s >= 1; s >>= 1) sum += __shfl_xor(sum, s);
      o = v - mx - logf(sum);
    }
    if (lane < D) {
      if constexpr (OUTF32) ((float*)dstv)[(size_t)wid * ldd + lane] = o;
      else ((unsigned short*)dstv)[(size_t)wid * ldd + lane] = f2bf(o);
    }
  }
}

// ---------------- launcher ----------------
extern "C" void kernel_launch(void* const* d_in, const int* in_sizes, int n_in,
                              void* d_out, int out_size, void* d_ws, size_t ws_size,
                              hipStream_t stream) {
  const float* x    = (const float*)d_in[0];
  const int*   ei   = (const int*)d_in[1];
  const float* eig  = (const float*)d_in[2];
  const float* W1   = (const float*)d_in[3];
  const float* b1   = (const float*)d_in[4];
  const float* W2   = (const float*)d_in[5];
  const float* b2   = (const float*)d_in[6];
  const float* linW = (const float*)d_in[7];
  const float* W3   = (const float*)d_in[8];
  const float* b3   = (const float*)d_in[9];
  float* out = (float*)d_out;

  const int N = in_sizes[0] / 512;
  const int E = in_sizes[1] / 2;

  char* ws = (char*)d_ws;
  size_t off = 0;
  auto alloc = [&](size_t bytes) { char* p = ws + off; off = ws_align(off + bytes); return p; };
  int*   rowA   = (int*)alloc((size_t)E * 4);
  int*   colA   = (int*)alloc((size_t)E * 4);
  int*   csr    = (int*)alloc((size_t)E * 4);
  int*   deg    = (int*)alloc((size_t)N * 4);
  int*   offs   = (int*)alloc((size_t)(N + 1) * 4);
  int*   cursor = (int*)alloc((size_t)N * 4);
  int*   bsum   = (int*)alloc(4096);
  int*   flag   = (int*)alloc(256);
  float* dis    = (float*)alloc((size_t)N * 4);
  unsigned short* F = (unsigned short*)alloc((size_t)N * 128 * 2);  // conv GEMM outputs, bf16
  unsigned short* G = (unsigned short*)alloc((size_t)N * 128 * 2);  // h1 then hcat, bf16
  unsigned short* WT1 = (unsigned short*)alloc(128 * 512 * 2);
  unsigned short* WT2 = (unsigned short*)alloc(64 * 128 * 2);
  unsigned short* WTl = (unsigned short*)alloc(64 * 128 * 2);
  unsigned short* WT3 = (unsigned short*)alloc(48 * 128 * 2);

  hipMemsetAsync(deg, 0, (size_t)N * 4, stream);
  hipMemsetAsync(cursor, 0, (size_t)N * 4, stream);

  const int gE = (E + BLK - 1) / BLK;
  const int gN = (N + BLK - 1) / BLK;

  k_detect<<<1, 1, 0, stream>>>(ei, flag);
  k_convert<<<gE, BLK, 0, stream>>>(ei, flag, rowA, colA, E);
  k_deg<<<gE, BLK, 0, stream>>>(colA, deg, E);
  k_dis<<<gN, BLK, 0, stream>>>(deg, dis, N);
  k_scan1<<<gN, BLK, 0, stream>>>(deg, offs, bsum, N);
  k_scan2<<<1, BLK, 0, stream>>>(bsum, gN);
  k_scan3<<<gN, BLK, 0, stream>>>(offs, bsum, N, E);
  k_scatter<<<gE, BLK, 0, stream>>>(rowA, colA, offs, cursor, csr, E);

  // weight conversions (tiny)
  k_wt<512, 128, 128><<<(128 * 512 + BLK - 1) / BLK, BLK, 0, stream>>>(W1, WT1);
  k_wt<128, 64, 64><<<(64 * 128 + BLK - 1) / BLK, BLK, 0, stream>>>(W2, WT2);
  k_wt<128, 64, 64><<<(64 * 128 + BLK - 1) / BLK, BLK, 0, stream>>>(linW, WTl);
  k_wt<128, 40, 48><<<(48 * 128 + BLK - 1) / BLK, BLK, 0, stream>>>(W3, WT3);

  const int gG2 = (N + 127) / 128;    // MFMA GEMM blocks (MR=2 -> 128 rows/block)
  const int gA = (N + 3) / 4;         // agg blocks (4 waves/block)

  // conv1: g1 = (x @ W1)*dis ; h1 = relu(dis*(g1[v]+sum) + b1)   [h1 -> G, bf16]
  k_mgemm<512, 8, 2, true><<<gG2, BLK, 0, stream>>>(x, WT1, dis, F, 128, 128, N);
  k_agg<128, true, false, false><<<gA, BLK, 0, stream>>>(F, 128, dis, b1, offs, csr, G, 128, N);
  // conv2: g2 = (h1 @ W2)*dis ; spectral xp = eig @ linW into right half of G
  k_mgemm<128, 4, 2, false><<<gG2, BLK, 0, stream>>>(G, WT2, dis, F, 64, 64, N);
  k_mgemm<128, 4, 2, true><<<gG2, BLK, 0, stream>>>(eig, WTl, nullptr, G + 64, 128, 64, N);
  k_agg<64, true, false, false><<<gA, BLK, 0, stream>>>(F, 64, dis, b2, offs, csr, G, 128, N);
  // conv3: g3 = (hcat @ W3)*dis ; out = log_softmax(dis*(g3[v]+sum)+b3)  [fp32 out]
  k_mgemm<128, 3, 2, false><<<gG2, BLK, 0, stream>>>(G, WT3, dis, F, 40, 40, N);
  k_agg<40, false, true, true><<<gA, BLK, 0, stream>>>(F, 40, dis, b3, offs, csr, out, 40, N);
}